// Round 18
// baseline (122.293 us; speedup 1.0000x reference)
//
#include <hip/hip_runtime.h>

typedef float  v4f __attribute__((ext_vector_type(4)));
typedef float  v2f __attribute__((ext_vector_type(2)));
typedef short  v8s __attribute__((ext_vector_type(8)));
typedef uint   v4u __attribute__((ext_vector_type(4)));

#define Hd   128
#define Wd   128
#define HW   (Hd*Wd)
#define CIN  64
#define COUT 64

// 2-row block strip: rows [ho-2, ho+3] x cols [wo0-2, wo0+34]
#define SR2   6
#define SC2   37
#define SCH2  (SR2*SC2*8)   // 1776 16B-chunks = 28416 B

__device__ __forceinline__ uint f2bf_rn(float v) {
  uint u = __builtin_bit_cast(uint, v);
  u += 0x7FFFu + ((u >> 16) & 1u);
  return u >> 16;
}

__device__ __forceinline__ void split_bf(float v, uint& h, uint& l) {
  uint u = __builtin_bit_cast(uint, v);
  uint r = u + 0x7FFFu + ((u >> 16) & 1u);
  h = r >> 16;
  float hf = __builtin_bit_cast(float, (r >> 16) << 16);
  float lf = v - hf;
  l = __builtin_bit_cast(uint, lf) >> 16;
}

// unpack a bf16 pair (lo ushort = even ch, hi ushort = odd ch) to 2 floats
__device__ __forceinline__ v2f bfpair(uint u) {
  v2f r;
  r.x = __builtin_bit_cast(float, u << 16);
  r.y = __builtin_bit_cast(float, u & 0xFFFF0000u);
  return r;
}

// ---- repack weights ----
__global__ __launch_bounds__(256) void repack(
    const float* __restrict__ w_off, const float* __restrict__ w,
    ushort* __restrict__ woff_t, ushort* __restrict__ whi,
    ushort* __restrict__ wlo) {
  int i = blockIdx.x * 256 + threadIdx.x;        // 0..36863 (=64*576)
  int co = i / 576, k = i - co * 576;
  int kk = k >> 6, ci = k & 63;
  float wv = w[(co * 64 + ci) * 9 + kk];
  uint h, l;
  split_bf(wv, h, l);
  whi[i] = (ushort)h;
  wlo[i] = (ushort)l;
  if (i < 32 * 576) {
    float v = (co < 18) ? w_off[(co * 64 + ci) * 9 + kk] : 0.f;
    woff_t[i] = (ushort)f2bf_rn(v);
  }
}

// ---- NCHW fp32 -> NHWC bf16 transpose ----
__global__ __launch_bounds__(256) void transpose_nhwc(
    const float* __restrict__ x, ushort* __restrict__ x_t) {
  __shared__ ushort tile[128][72];
  const int t  = threadIdx.x;
  const int by = blockIdx.x;                     // b*128 + y
  const float* xp = x + (size_t)(by >> 7) * (CIN * HW) + (size_t)(by & 127) * Wd;
#pragma unroll
  for (int r = 0; r < 32; ++r) {
    int idx = r * 256 + t;
    int ci = idx >> 7, xw = idx & 127;
    tile[xw][ci] = (ushort)f2bf_rn(xp[(size_t)ci * HW + xw]);
  }
  __syncthreads();
  ushort* op = x_t + (size_t)by * (Wd * CIN);
#pragma unroll
  for (int r = 0; r < 4; ++r) {
    int c = r * 256 + t;
    int xw = c >> 3, q = c & 7;
    v4u v = *(const v4u*)&tile[xw][q * 8];
    *(v4u*)(op + xw * 64 + q * 8) = v;
  }
}

// packed bilinear blend core: 4 taps (pairs of channels) -> bf16x8 fragment
__device__ __forceinline__ v8s blend_core(
    v4u t00, v4u t01, v4u t10, v4u t11,
    float w00, float w01, float w10, float w11) {
  const v2f w00v = {w00, w00}, w01v = {w01, w01};
  const v2f w10v = {w10, w10}, w11v = {w11, w11};
  uint ph[4];
#pragma unroll
  for (int j = 0; j < 4; ++j) {
    v2f v = bfpair(t00[j]) * w00v;
    v = bfpair(t01[j]) * w01v + v;        // -> v_pk_fma_f32
    v = bfpair(t10[j]) * w10v + v;
    v = bfpair(t11[j]) * w11v + v;
    uint r;
    asm("v_cvt_pk_bf16_f32 %0, %1, %2" : "=v"(r) : "v"(v.x), "v"(v.y));
    ph[j] = r;
  }
  v4u q = {ph[0], ph[1], ph[2], ph[3]};
  return __builtin_bit_cast(v8s, q);
}

// branch-free fast path: unconditional clamped strip reads
__device__ __forceinline__ v8s blend_fast(
    const v4u* __restrict__ strip, int yrc, int xrc, int k4,
    float w00, float w01, float w10, float w11) {
  int cA = (yrc * SC2 + xrc) * 8 + k4;
  int cB = cA + 8;
  int sA = xrc & 7, sB = (xrc + 1) & 7;
  v4u t00 = strip[cA ^ sA];
  v4u t01 = strip[cB ^ sB];
  v4u t10 = strip[(cA + SC2 * 8) ^ sA];
  v4u t11 = strip[(cB + SC2 * 8) ^ sB];
  return blend_core(t00, t01, t10, t11, w00, w01, w10, w11);
}

// rare repair path: per-lane global gather (clamped image coords)
__device__ __forceinline__ v8s blend_glob(
    const ushort* __restrict__ xtb, int y0i, int x0i, int k4,
    float w00, float w01, float w10, float w11) {
  int y0c = min(max(y0i, 0), 127), y1c = min(max(y0i + 1, 0), 127);
  int x0c = min(max(x0i, 0), 127), x1c = min(max(x0i + 1, 0), 127);
  v4u t00 = *(const v4u*)(xtb + ((y0c << 7) + x0c) * 64 + k4 * 8);
  v4u t01 = *(const v4u*)(xtb + ((y0c << 7) + x1c) * 64 + k4 * 8);
  v4u t10 = *(const v4u*)(xtb + ((y1c << 7) + x0c) * 64 + k4 * 8);
  v4u t11 = *(const v4u*)(xtb + ((y1c << 7) + x1c) * 64 + k4 * 8);
  return blend_core(t00, t01, t10, t11, w00, w01, w10, w11);
}

// per-pixel, per-kk weight/position computation from REGISTER dy/dx
struct PixW {
  float w00, w01, w10, w11;
  int yrc, xrc, y0i, x0i;
  bool ok;          // in-strip-index-range (weights already handle image OOB)
};
__device__ __forceinline__ PixW pixw(float dy, float dxo, float byf,
                                     float bxf, int row0, int x0s) {
  PixW r;
  float py  = byf + dy;
  float pxf = bxf + dxo;
  float y0f = floorf(py), x0f = floorf(pxf);
  float wy1 = py - y0f, wy0 = 1.f - wy1;
  float wx1 = pxf - x0f, wx0 = 1.f - wx1;
  bool vy0 = (y0f >= 0.f)  && (y0f < 128.f);
  bool vy1 = (y0f >= -1.f) && (y0f < 127.f);
  bool vx0 = (x0f >= 0.f)  && (x0f < 128.f);
  bool vx1 = (x0f >= -1.f) && (x0f < 127.f);
  r.w00 = wy0 * wx0 * ((vy0 && vx0) ? 1.f : 0.f);
  r.w01 = wy0 * wx1 * ((vy0 && vx1) ? 1.f : 0.f);
  r.w10 = wy1 * wx0 * ((vy1 && vx0) ? 1.f : 0.f);
  r.w11 = wy1 * wx1 * ((vy1 && vx1) ? 1.f : 0.f);
  r.y0i = (int)y0f; r.x0i = (int)x0f;
  int yr = r.y0i - row0, xr = r.x0i - x0s;
  r.yrc = min(max(yr, 0), 4);
  r.xrc = min(max(xr, 0), 35);
  r.ok  = (yr == r.yrc) && (xr == r.xrc);
  return r;
}

// ===== wave = (row, kst-half): dedup'd blend; cross-wave ci reduction =====
__global__ __launch_bounds__(256, 3) void dconv10(
    const ushort* __restrict__ x_t, const float* __restrict__ b_off,
    const ushort* __restrict__ woff_t, const ushort* __restrict__ whi,
    const ushort* __restrict__ wlo, float* __restrict__ out) {

  __shared__ v4u   strip[SCH2];        // 28416 B
  __shared__ float pypx[2][32][20];    //  5120 B (pixel-major, padded)
  __shared__ float redu[2][32][64];    // 16384 B: [row][j=c*8+p*4+jj][lane]

  const int t    = threadIdx.x;
  const int lane = t & 63;
  const int wv   = t >> 6;
  const int lo16 = lane & 15, hi2 = lane >> 4;

  // 2048 blocks: 8 XCDs x (one batch image each: 64 row-pairs x 4 col-tiles)
  const int wid = ((blockIdx.x & 7) << 8) | (blockIdx.x >> 3);
  const int b   = wid >> 8;
  const int rem = wid & 255;
  const int ho  = (rem >> 2) << 1;         // even row: 0..126
  const int wo0 = (rem & 3) << 5;          // 0,32,64,96
  const ushort* xtb = x_t + (size_t)b * (HW * CIN);

  // ---- stage strip: rows [ho-2, ho+3] x cols [wo0-2, wo0+34], OOB zeros
  const int row0 = ho - 2, x0s = wo0 - 2;
#pragma unroll
  for (int it = 0; it < 7; ++it) {
    int ch = it * 256 + t;
    if (ch < SCH2) {
      int k8 = ch & 7;
      int rc = ch >> 3;
      int c  = rc % SC2;
      int r  = rc / SC2;
      int y  = row0 + r, xg = x0s + c;
      v4u v = {0u, 0u, 0u, 0u};
      if (y >= 0 && y < Hd && xg >= 0 && xg < Wd)
        v = *(const v4u*)(xtb + ((y << 7) + xg) * 64 + k8 * 8);
      strip[ch ^ (c & 7)] = v;   // granule swizzle: slot k8^(c&7)
    }
  }
  __syncthreads();

  // ---- phase A: offset conv; wave -> (rowA = wv>>1, px-half = wv&1)
  v4f oacc0 = {0.f, 0.f, 0.f, 0.f};
  v4f oacc1 = {0.f, 0.f, 0.f, 0.f};
  const int rowA = wv >> 1;
  const int pxA  = ((wv & 1) << 4) + lo16;      // 0..31 within row
#pragma unroll
  for (int kk = 0; kk < 9; ++kk) {
    const int rr = kk / 3, dxk = kk % 3;
    const int sr = rowA + rr + 1;                 // strip row of integer tap
    const int c  = pxA + 1 + dxk;                 // strip col
#pragma unroll
    for (int kst = 0; kst < 2; ++kst) {
      const int k4 = kst * 4 + hi2;
      v8s bfr = *(const v8s*)&strip[(((sr * SC2 + c) * 8) + k4) ^ (c & 7)];
      v8s a0  = *(const v8s*)(woff_t + (0  + lo16) * 576 + kk * 64 + kst * 32 + hi2 * 8);
      v8s a1  = *(const v8s*)(woff_t + (16 + lo16) * 576 + kk * 64 + kst * 32 + hi2 * 8);
      oacc0 = __builtin_amdgcn_mfma_f32_16x16x32_bf16(a0, bfr, oacc0, 0, 0, 0);
      oacc1 = __builtin_amdgcn_mfma_f32_16x16x32_bf16(a1, bfr, oacc1, 0, 0, 0);
    }
  }
  {
#pragma unroll
    for (int j = 0; j < 4; ++j) {
      int oc = hi2 * 4 + j;
      pypx[rowA][pxA][oc] = oacc0[j] + b_off[oc];
    }
    if (hi2 == 0) {
#pragma unroll
      for (int j = 0; j < 2; ++j)
        pypx[rowA][pxA][16 + j] = oacc1[j] + b_off[16 + j];
    }
  }
  __syncthreads();

  // ---- phase B: wave -> (rowB = wv>>1, ci-half ksh = wv&1)
  //      Each wave: 32 px x 64 co, but only its 32-ci half of K.
  v4f acc[4][2];
#pragma unroll
  for (int c = 0; c < 4; ++c)
#pragma unroll
    for (int p = 0; p < 2; ++p) acc[c][p] = (v4f){0.f, 0.f, 0.f, 0.f};

  const int rowB = wv >> 1;
  const int ksh  = wv & 1;
  const int hoB  = ho + rowB;
  const int pr0  = lo16, pr1 = lo16 + 16;
  const int k4   = ksh * 4 + hi2;          // this wave's granule (8 ci)

  // hoist all 18 dy/dx per pixel into registers (vector LDS reads)
  float pyA[18], pyB[18];
  {
    const float* p0 = &pypx[rowB][pr0][0];
    const float* p1 = &pypx[rowB][pr1][0];
#pragma unroll
    for (int i = 0; i < 4; ++i) {
      v4f a = *(const v4f*)(p0 + i * 4);
      v4f bb = *(const v4f*)(p1 + i * 4);
#pragma unroll
      for (int j = 0; j < 4; ++j) { pyA[i * 4 + j] = a[j]; pyB[i * 4 + j] = bb[j]; }
    }
    v2f a2 = *(const v2f*)(p0 + 16);
    v2f b2 = *(const v2f*)(p1 + 16);
    pyA[16] = a2.x; pyA[17] = a2.y;
    pyB[16] = b2.x; pyB[17] = b2.y;
  }

#pragma unroll
  for (int kk = 0; kk < 9; ++kk) {
    const int rr = kk / 3, dxk = kk % 3;
    const float byf  = (float)(hoB - 1 + rr);
    const float bxf0 = (float)(wo0 + pr0 - 1 + dxk);
    const float bxf1 = (float)(wo0 + pr1 - 1 + dxk);

    PixW a  = pixw(pyA[2 * kk], pyA[2 * kk + 1], byf, bxf0, row0, x0s);
    PixW bw = pixw(pyB[2 * kk], pyB[2 * kk + 1], byf, bxf1, row0, x0s);
    const bool viol = (!a.ok) || (!bw.ok);

    // ONE blend per pixel per kk (dedup'd: this wave's k4 granule only)
    v8s bh0 = blend_fast(strip, a.yrc, a.xrc, k4, a.w00, a.w01, a.w10, a.w11);
    v8s bh1 = blend_fast(strip, bw.yrc, bw.xrc, k4, bw.w00, bw.w01, bw.w10, bw.w11);
    if (__any(viol)) {
      if (!a.ok)
        bh0 = blend_glob(xtb, a.y0i, a.x0i, k4, a.w00, a.w01, a.w10, a.w11);
      if (!bw.ok)
        bh1 = blend_glob(xtb, bw.y0i, bw.x0i, k4, bw.w00, bw.w01, bw.w10, bw.w11);
    }

    const int ko = kk * 64 + ksh * 32 + hi2 * 8;
#pragma unroll
    for (int c = 0; c < 4; ++c) {
      v8s ah = *(const v8s*)(whi + (c * 16 + lo16) * 576 + ko);
      v8s al = *(const v8s*)(wlo + (c * 16 + lo16) * 576 + ko);
      // alternate accumulators: adjacent MFMAs never share an acc
      acc[c][0] = __builtin_amdgcn_mfma_f32_16x16x32_bf16(ah, bh0, acc[c][0], 0, 0, 0);
      acc[c][1] = __builtin_amdgcn_mfma_f32_16x16x32_bf16(ah, bh1, acc[c][1], 0, 0, 0);
      acc[c][0] = __builtin_amdgcn_mfma_f32_16x16x32_bf16(al, bh0, acc[c][0], 0, 0, 0);
      acc[c][1] = __builtin_amdgcn_mfma_f32_16x16x32_bf16(al, bh1, acc[c][1], 0, 0, 0);
    }
  }

  // ---- cross-wave ci reduction: ksh=1 writes partials, ksh=0 adds+stores
  if (ksh == 1) {
#pragma unroll
    for (int c = 0; c < 4; ++c)
#pragma unroll
      for (int p = 0; p < 2; ++p)
#pragma unroll
        for (int jj = 0; jj < 4; ++jj)
          redu[rowB][c * 8 + p * 4 + jj][lane] = acc[c][p][jj];
  }
  __syncthreads();
  if (ksh == 0) {
    const int wo_b = wo0 + lo16;
#pragma unroll
    for (int c = 0; c < 4; ++c) {
#pragma unroll
      for (int p = 0; p < 2; ++p) {
#pragma unroll
        for (int jj = 0; jj < 4; ++jj) {
          float s = acc[c][p][jj] + redu[rowB][c * 8 + p * 4 + jj][lane];
          int co = c * 16 + hi2 * 4 + jj;
          out[(((size_t)b * COUT + co) * Hd + hoB) * Wd + wo_b + p * 16] = s;
        }
      }
    }
  }
}

// =================== fallback (round-3 kernel, NCHW fp32 gathers) ==========
__global__ __launch_bounds__(256, 4) void dconv_old(
    const float* __restrict__ x, const float* __restrict__ b_off,
    const ushort* __restrict__ woff_t, const ushort* __restrict__ whi,
    const ushort* __restrict__ wlo, float* __restrict__ out) {

  __shared__ uint4 colsA[64 * 8];
  __shared__ uint4 colsB[64 * 8];
  __shared__ float pypx[18][64];

  const int t    = threadIdx.x;
  const int lane = t & 63;
  const int wv   = t >> 6;
  const int lo16 = lane & 15, hi2 = lane >> 4;
  const int wid = ((blockIdx.x & 7) << 8) | (blockIdx.x >> 3);
  const int b   = wid >> 8;
  const int ho  = (wid >> 1) & 127;
  const int wo0 = (wid & 1) << 6;
  const int px = t & 63;
  const int g  = t >> 6;
  const float* xb = x + (size_t)b * (CIN * HW);

  v4f oacc0 = {0.f, 0.f, 0.f, 0.f};
  v4f oacc1 = {0.f, 0.f, 0.f, 0.f};

  for (int kk = 0; kk < 9; ++kk) {
    if (kk) __syncthreads();
    {
      int yy = ho - 1 + kk / 3;
      int xx = wo0 + px - 1 + kk % 3;
      bool vok = (yy >= 0) && (yy < Hd) && (xx >= 0) && (xx < Wd);
      const float* xp = xb + (size_t)(g * 16) * HW + yy * Wd + xx;
      uint pk[8];
#pragma unroll
      for (int u = 0; u < 16; u += 2) {
        float a0 = vok ? xp[(u + 0) * HW] : 0.f;
        float a1 = vok ? xp[(u + 1) * HW] : 0.f;
        pk[u >> 1] = f2bf_rn(a0) | (f2bf_rn(a1) << 16);
      }
      uint4 q0 = {pk[0], pk[1], pk[2], pk[3]};
      uint4 q1 = {pk[4], pk[5], pk[6], pk[7]};
      int base = px * 8, s = px & 7;
      colsA[base + ((g * 2 + 0) ^ s)] = q0;
      colsA[base + ((g * 2 + 1) ^ s)] = q1;
    }
    __syncthreads();
    int pxr = wv * 16 + lo16;
#pragma unroll
    for (int kst = 0; kst < 2; ++kst) {
      const v8s* ap0 = (const v8s*)(woff_t + (0  + lo16) * 576 + kk * 64 + kst * 32 + hi2 * 8);
      const v8s* ap1 = (const v8s*)(woff_t + (16 + lo16) * 576 + kk * 64 + kst * 32 + hi2 * 8);
      const v8s* bp  = (const v8s*)&colsA[pxr * 8 + ((kst * 4 + hi2) ^ (pxr & 7))];
      v8s bfr = *bp;
      oacc0 = __builtin_amdgcn_mfma_f32_16x16x32_bf16(*ap0, bfr, oacc0, 0, 0, 0);
      oacc1 = __builtin_amdgcn_mfma_f32_16x16x32_bf16(*ap1, bfr, oacc1, 0, 0, 0);
    }
  }
  {
    int pxw = wv * 16 + lo16;
#pragma unroll
    for (int j = 0; j < 4; ++j) {
      int oc = hi2 * 4 + j;
      pypx[oc][pxw] = oacc0[j] + b_off[oc];
    }
    if (hi2 == 0) {
#pragma unroll
      for (int j = 0; j < 2; ++j)
        pypx[16 + j][pxw] = oacc1[j] + b_off[16 + j];
    }
  }
  __syncthreads();

  v4f acc[2][2];
#pragma unroll
  for (int a = 0; a < 2; ++a)
#pragma unroll
    for (int c = 0; c < 2; ++c) acc[a][c] = (v4f){0.f, 0.f, 0.f, 0.f};

  const int co0 = (wv & 1) << 5;
  const int px0 = (wv >> 1) << 5;

  for (int kk = 0; kk < 9; ++kk) {
    if (kk) __syncthreads();
    {
      float dy = pypx[2 * kk][px], dx = pypx[2 * kk + 1][px];
      float py  = (float)(ho - 1 + kk / 3) + dy;
      float pxf = (float)(wo0 + px - 1 + kk % 3) + dx;
      float y0f = floorf(py), x0f = floorf(pxf);
      float wy1 = py - y0f,  wy0 = 1.f - wy1;
      float wx1 = pxf - x0f, wx0 = 1.f - wx1;
      bool vy0 = (y0f >= 0.f)  && (y0f < (float)Hd);
      bool vy1 = (y0f >= -1.f) && (y0f < (float)(Hd - 1));
      bool vx0 = (x0f >= 0.f)  && (x0f < (float)Wd);
      bool vx1 = (x0f >= -1.f) && (x0f < (float)(Wd - 1));
      float w00 = wy0 * wx0 * ((vy0 && vx0) ? 1.f : 0.f);
      float w01 = wy0 * wx1 * ((vy0 && vx1) ? 1.f : 0.f);
      float w10 = wy1 * wx0 * ((vy1 && vx0) ? 1.f : 0.f);
      float w11 = wy1 * wx1 * ((vy1 && vx1) ? 1.f : 0.f);
      int y0  = (int)fminf(fmaxf(y0f,       0.f), (float)(Hd - 1));
      int y1  = (int)fminf(fmaxf(y0f + 1.f, 0.f), (float)(Hd - 1));
      int x0i = (int)fminf(fmaxf(x0f,       0.f), (float)(Wd - 1));
      int x1i = (int)fminf(fmaxf(x0f + 1.f, 0.f), (float)(Wd - 1));
      const float* xp  = xb + (size_t)(g * 16) * HW;
      const float* p00 = xp + y0 * Wd + x0i;
      const float* p01 = xp + y0 * Wd + x1i;
      const float* p10 = xp + y1 * Wd + x0i;
      const float* p11 = xp + y1 * Wd + x1i;
      uint ph[8], pl[8];
#pragma unroll
      for (int u = 0; u < 16; u += 2) {
        float v0 = w00 * p00[u * HW] + w01 * p01[u * HW] +
                   w10 * p10[u * HW] + w11 * p11[u * HW];
        float v1 = w00 * p00[(u + 1) * HW] + w01 * p01[(u + 1) * HW] +
                   w10 * p10[(u + 1) * HW] + w11 * p11[(u + 1) * HW];
        uint h0, l0, h1, l1;
        split_bf(v0, h0, l0);
        split_bf(v1, h1, l1);
        ph[u >> 1] = h0 | (h1 << 16);
        pl[u >> 1] = l0 | (l1 << 16);
      }
      uint4 qh0 = {ph[0], ph[1], ph[2], ph[3]};
      uint4 qh1 = {ph[4], ph[5], ph[6], ph[7]};
      uint4 ql0 = {pl[0], pl[1], pl[2], pl[3]};
      uint4 ql1 = {pl[4], pl[5], pl[6], pl[7]};
      int base = px * 8, s = px & 7;
      colsA[base + ((g * 2 + 0) ^ s)] = qh0;
      colsA[base + ((g * 2 + 1) ^ s)] = qh1;
      colsB[base + ((g * 2 + 0) ^ s)] = ql0;
      colsB[base + ((g * 2 + 1) ^ s)] = ql1;
    }
    __syncthreads();

#pragma unroll
    for (int kst = 0; kst < 2; ++kst) {
      const int ko = kk * 64 + kst * 32 + hi2 * 8;
      v8s ah0 = *(const v8s*)(whi + (co0 +      lo16) * 576 + ko);
      v8s ah1 = *(const v8s*)(whi + (co0 + 16 + lo16) * 576 + ko);
      v8s al0 = *(const v8s*)(wlo + (co0 +      lo16) * 576 + ko);
      v8s al1 = *(const v8s*)(wlo + (co0 + 16 + lo16) * 576 + ko);
      int pr0 = px0 + lo16, pr1 = px0 + 16 + lo16;
      int k4 = kst * 4 + hi2;
      v8s bh0 = *(const v8s*)&colsA[pr0 * 8 + (k4 ^ (pr0 & 7))];
      v8s bh1 = *(const v8s*)&colsA[pr1 * 8 + (k4 ^ (pr1 & 7))];
      v8s bl0 = *(const v8s*)&colsB[pr0 * 8 + (k4 ^ (pr0 & 7))];
      v8s bl1 = *(const v8s*)&colsB[pr1 * 8 + (k4 ^ (pr1 & 7))];

      acc[0][0] = __builtin_amdgcn_mfma_f32_16x16x32_bf16(ah0, bh0, acc[0][0], 0, 0, 0);
      acc[0][0] = __builtin_amdgcn_mfma_f32_16x16x32_bf16(ah0, bl0, acc[0][0], 0, 0, 0);
      acc[0][0] = __builtin_amdgcn_mfma_f32_16x16x32_bf16(al0, bh0, acc[0][0], 0, 0, 0);
      acc[0][1] = __builtin_amdgcn_mfma_f32_16x16x32_bf16(ah0, bh1, acc[0][1], 0, 0, 0);
      acc[0][1] = __builtin_amdgcn_mfma_f32_16x16x32_bf16(ah0, bl1, acc[0][1], 0, 0, 0);
      acc[0][1] = __builtin_amdgcn_mfma_f32_16x16x32_bf16(al0, bh1, acc[0][1], 0, 0, 0);
      acc[1][0] = __builtin_amdgcn_mfma_f32_16x16x32_bf16(ah1, bh0, acc[1][0], 0, 0, 0);
      acc[1][0] = __builtin_amdgcn_mfma_f32_16x16x32_bf16(ah1, bl0, acc[1][0], 0, 0, 0);
      acc[1][0] = __builtin_amdgcn_mfma_f32_16x16x32_bf16(al1, bh0, acc[1][0], 0, 0, 0);
      acc[1][1] = __builtin_amdgcn_mfma_f32_16x16x32_bf16(ah1, bh1, acc[1][1], 0, 0, 0);
      acc[1][1] = __builtin_amdgcn_mfma_f32_16x16x32_bf16(ah1, bl1, acc[1][1], 0, 0, 0);
      acc[1][1] = __builtin_amdgcn_mfma_f32_16x16x32_bf16(al1, bh1, acc[1][1], 0, 0, 0);
    }
  }

  const int wo_b = wo0 + px0 + lo16;
#pragma unroll
  for (int ct = 0; ct < 2; ++ct) {
#pragma unroll
    for (int pt = 0; pt < 2; ++pt) {
#pragma unroll
      for (int j = 0; j < 4; ++j) {
        int co = co0 + ct * 16 + hi2 * 4 + j;
        out[(((size_t)b * COUT + co) * Hd + ho) * Wd + wo_b + pt * 16] = acc[ct][pt][j];
      }
    }
  }
}

extern "C" void kernel_launch(void* const* d_in, const int* in_sizes, int n_in,
                              void* d_out, int out_size, void* d_ws, size_t ws_size,
                              hipStream_t stream) {
  const float* x     = (const float*)d_in[0];
  const float* w_off = (const float*)d_in[1];
  const float* b_off = (const float*)d_in[2];
  const float* w     = (const float*)d_in[3];
  float* out = (float*)d_out;

  const size_t XT_ELT = (size_t)8 * HW * CIN;          // 8,388,608 ushorts
  const size_t NEED   = XT_ELT * 2 + 2u * (18432 + 36864 + 36864);

  ushort* base = (ushort*)d_ws;
  ushort *x_t, *woff_t, *whi, *wlo;
  bool fast = (ws_size >= NEED);
  if (fast) {
    x_t    = base;
    woff_t = base + XT_ELT;
  } else {
    x_t    = nullptr;
    woff_t = base;
  }
  whi = woff_t + 18432;
  wlo = whi + 36864;

  repack<<<144, 256, 0, stream>>>(w_off, w, woff_t, whi, wlo);

  if (fast) {
    transpose_nhwc<<<8 * Hd, 256, 0, stream>>>(x, x_t);
    dconv10<<<2048, 256, 0, stream>>>(x_t, b_off, woff_t, whi, wlo, out);
  } else {
    dconv_old<<<2048, 256, 0, stream>>>(x, b_off, woff_t, whi, wlo, out);
  }
}

// Round 20
// 69.359 us; speedup vs baseline: 1.7632x; 1.7632x over previous
//
#include <hip/hip_runtime.h>

typedef float  v4f __attribute__((ext_vector_type(4)));
typedef float  v2f __attribute__((ext_vector_type(2)));
typedef short  v8s __attribute__((ext_vector_type(8)));
typedef uint   v4u __attribute__((ext_vector_type(4)));

#define Hd   128
#define Wd   128
#define HW   (Hd*Wd)
#define CIN  64
#define COUT 64

// 2-row block strip: rows [ho-2, ho+3] x cols [wo0-2, wo0+34]
#define SR2   6
#define SC2   37
#define SCH2  (SR2*SC2*8)   // 1776 16B-chunks = 28416 B

__device__ __forceinline__ uint f2bf_rn(float v) {
  uint u = __builtin_bit_cast(uint, v);
  u += 0x7FFFu + ((u >> 16) & 1u);
  return u >> 16;
}

__device__ __forceinline__ void split_bf(float v, uint& h, uint& l) {
  uint u = __builtin_bit_cast(uint, v);
  uint r = u + 0x7FFFu + ((u >> 16) & 1u);
  h = r >> 16;
  float hf = __builtin_bit_cast(float, (r >> 16) << 16);
  float lf = v - hf;
  l = __builtin_bit_cast(uint, lf) >> 16;
}

// unpack a bf16 pair (lo ushort = even ch, hi ushort = odd ch) to 2 floats
__device__ __forceinline__ v2f bfpair(uint u) {
  v2f r;
  r.x = __builtin_bit_cast(float, u << 16);
  r.y = __builtin_bit_cast(float, u & 0xFFFF0000u);
  return r;
}

// ---- repack weights: FRAGMENT-CONTIGUOUS layouts (512-elt fragments) ----
// whi2/wlo2: i = ((kk*2+ksh)*4 + c)*512 + lane*8 + e
//            co = c*16 + (lane&15), ci = ksh*32 + (lane>>4)*8 + e
// woff2:     i = ((kk*2+kst)*2 + r2)*512 + lane*8 + e
//            oc = r2*16 + (lane&15), ci = kst*32 + (lane>>4)*8 + e
__global__ __launch_bounds__(256) void repack_frag(
    const float* __restrict__ w_off, const float* __restrict__ w,
    ushort* __restrict__ woff2, ushort* __restrict__ whi2,
    ushort* __restrict__ wlo2) {
  int i = blockIdx.x * 256 + threadIdx.x;        // 0..36863
  {
    int e    = i & 7;
    int lo16 = (i >> 3) & 15;
    int hi2  = (i >> 7) & 3;
    int c    = (i >> 9) & 3;
    int ksh  = (i >> 11) & 1;
    int kk   = i >> 12;                          // 0..8
    int co = c * 16 + lo16;
    int ci = ksh * 32 + hi2 * 8 + e;
    float wv = w[(co * 64 + ci) * 9 + kk];
    uint h, l;
    split_bf(wv, h, l);
    whi2[i] = (ushort)h;
    wlo2[i] = (ushort)l;
  }
  if (i < 18432) {
    int e    = i & 7;
    int lo16 = (i >> 3) & 15;
    int hi2  = (i >> 7) & 3;
    int r2   = (i >> 9) & 1;
    int kst  = (i >> 10) & 1;
    int kk   = i >> 11;                          // 0..8
    int oc = r2 * 16 + lo16;
    int ci = kst * 32 + hi2 * 8 + e;
    float v = (oc < 18) ? w_off[(oc * 64 + ci) * 9 + kk] : 0.f;
    woff2[i] = (ushort)f2bf_rn(v);
  }
}

// ---- old-layout repack (fallback path only) ----
__global__ __launch_bounds__(256) void repack_old(
    const float* __restrict__ w_off, const float* __restrict__ w,
    ushort* __restrict__ woff_t, ushort* __restrict__ whi,
    ushort* __restrict__ wlo) {
  int i = blockIdx.x * 256 + threadIdx.x;
  int co = i / 576, k = i - co * 576;
  int kk = k >> 6, ci = k & 63;
  float wv = w[(co * 64 + ci) * 9 + kk];
  uint h, l;
  split_bf(wv, h, l);
  whi[i] = (ushort)h;
  wlo[i] = (ushort)l;
  if (i < 32 * 576) {
    float v = (co < 18) ? w_off[(co * 64 + ci) * 9 + kk] : 0.f;
    woff_t[i] = (ushort)f2bf_rn(v);
  }
}

// ---- NCHW fp32 -> NHWC bf16 transpose ----
__global__ __launch_bounds__(256) void transpose_nhwc(
    const float* __restrict__ x, ushort* __restrict__ x_t) {
  __shared__ ushort tile[128][72];
  const int t  = threadIdx.x;
  const int by = blockIdx.x;                     // b*128 + y
  const float* xp = x + (size_t)(by >> 7) * (CIN * HW) + (size_t)(by & 127) * Wd;
#pragma unroll
  for (int r = 0; r < 32; ++r) {
    int idx = r * 256 + t;
    int ci = idx >> 7, xw = idx & 127;
    tile[xw][ci] = (ushort)f2bf_rn(xp[(size_t)ci * HW + xw]);
  }
  __syncthreads();
  ushort* op = x_t + (size_t)by * (Wd * CIN);
#pragma unroll
  for (int r = 0; r < 4; ++r) {
    int c = r * 256 + t;
    int xw = c >> 3, q = c & 7;
    v4u v = *(const v4u*)&tile[xw][q * 8];
    *(v4u*)(op + xw * 64 + q * 8) = v;
  }
}

// packed bilinear blend core: 4 taps (pairs of channels) -> bf16x8 fragment
__device__ __forceinline__ v8s blend_core(
    v4u t00, v4u t01, v4u t10, v4u t11,
    float w00, float w01, float w10, float w11) {
  const v2f w00v = {w00, w00}, w01v = {w01, w01};
  const v2f w10v = {w10, w10}, w11v = {w11, w11};
  uint ph[4];
#pragma unroll
  for (int j = 0; j < 4; ++j) {
    v2f v = bfpair(t00[j]) * w00v;
    v = bfpair(t01[j]) * w01v + v;        // -> v_pk_fma_f32
    v = bfpair(t10[j]) * w10v + v;
    v = bfpair(t11[j]) * w11v + v;
    uint r;
    asm("v_cvt_pk_bf16_f32 %0, %1, %2" : "=v"(r) : "v"(v.x), "v"(v.y));
    ph[j] = r;
  }
  v4u q = {ph[0], ph[1], ph[2], ph[3]};
  return __builtin_bit_cast(v8s, q);
}

// branch-free fast path: unconditional clamped strip reads
__device__ __forceinline__ v8s blend_fast(
    const v4u* __restrict__ strip, int yrc, int xrc, int k4,
    float w00, float w01, float w10, float w11) {
  int cA = (yrc * SC2 + xrc) * 8 + k4;
  int cB = cA + 8;
  int sA = xrc & 7, sB = (xrc + 1) & 7;
  v4u t00 = strip[cA ^ sA];
  v4u t01 = strip[cB ^ sB];
  v4u t10 = strip[(cA + SC2 * 8) ^ sA];
  v4u t11 = strip[(cB + SC2 * 8) ^ sB];
  return blend_core(t00, t01, t10, t11, w00, w01, w10, w11);
}

// rare repair path: per-lane global gather (clamped image coords)
__device__ __forceinline__ v8s blend_glob(
    const ushort* __restrict__ xtb, int y0i, int x0i, int k4,
    float w00, float w01, float w10, float w11) {
  int y0c = min(max(y0i, 0), 127), y1c = min(max(y0i + 1, 0), 127);
  int x0c = min(max(x0i, 0), 127), x1c = min(max(x0i + 1, 0), 127);
  v4u t00 = *(const v4u*)(xtb + ((y0c << 7) + x0c) * 64 + k4 * 8);
  v4u t01 = *(const v4u*)(xtb + ((y0c << 7) + x1c) * 64 + k4 * 8);
  v4u t10 = *(const v4u*)(xtb + ((y1c << 7) + x0c) * 64 + k4 * 8);
  v4u t11 = *(const v4u*)(xtb + ((y1c << 7) + x1c) * 64 + k4 * 8);
  return blend_core(t00, t01, t10, t11, w00, w01, w10, w11);
}

// per-pixel, per-kk weight/position computation from REGISTER dy/dx
struct PixW {
  float w00, w01, w10, w11;
  int yrc, xrc, y0i, x0i;
  bool ok;          // in-strip-index-range (weights already handle image OOB)
};
__device__ __forceinline__ PixW pixw(float dy, float dxo, float byf,
                                     float bxf, int row0, int x0s) {
  PixW r;
  float py  = byf + dy;
  float pxf = bxf + dxo;
  float y0f = floorf(py), x0f = floorf(pxf);
  float wy1 = py - y0f, wy0 = 1.f - wy1;
  float wx1 = pxf - x0f, wx0 = 1.f - wx1;
  bool vy0 = (y0f >= 0.f)  && (y0f < 128.f);
  bool vy1 = (y0f >= -1.f) && (y0f < 127.f);
  bool vx0 = (x0f >= 0.f)  && (x0f < 128.f);
  bool vx1 = (x0f >= -1.f) && (x0f < 127.f);
  r.w00 = wy0 * wx0 * ((vy0 && vx0) ? 1.f : 0.f);
  r.w01 = wy0 * wx1 * ((vy0 && vx1) ? 1.f : 0.f);
  r.w10 = wy1 * wx0 * ((vy1 && vx0) ? 1.f : 0.f);
  r.w11 = wy1 * wx1 * ((vy1 && vx1) ? 1.f : 0.f);
  r.y0i = (int)y0f; r.x0i = (int)x0f;
  int yr = r.y0i - row0, xr = r.x0i - x0s;
  r.yrc = min(max(yr, 0), 4);
  r.xrc = min(max(xr, 0), 35);
  r.ok  = (yr == r.yrc) && (xr == r.xrc);
  return r;
}

// ===== r18 structure + fragment-contiguous (coalesced) A-operand loads =====
__global__ __launch_bounds__(256, 3) void dconv12(
    const ushort* __restrict__ x_t, const float* __restrict__ b_off,
    const ushort* __restrict__ woff2, const ushort* __restrict__ whi2,
    const ushort* __restrict__ wlo2, float* __restrict__ out) {

  __shared__ v4u   strip[SCH2];        // 28416 B
  __shared__ float pypx[2][32][20];    //  5120 B (pixel-major, padded)
  __shared__ float redu[2][32][64];    // 16384 B: [row][j=c*8+p*4+jj][lane]

  const int t    = threadIdx.x;
  const int lane = t & 63;
  const int wv   = t >> 6;
  const int lo16 = lane & 15, hi2 = lane >> 4;
  const int lane8 = lane * 8;                  // A-frag per-lane offset

  // 2048 blocks: 8 XCDs x (one batch image each: 64 row-pairs x 4 col-tiles)
  const int wid = ((blockIdx.x & 7) << 8) | (blockIdx.x >> 3);
  const int b   = wid >> 8;
  const int rem = wid & 255;
  const int ho  = (rem >> 2) << 1;         // even row: 0..126
  const int wo0 = (rem & 3) << 5;          // 0,32,64,96
  const ushort* xtb = x_t + (size_t)b * (HW * CIN);

  // ---- stage strip: rows [ho-2, ho+3] x cols [wo0-2, wo0+34], OOB zeros
  const int row0 = ho - 2, x0s = wo0 - 2;
#pragma unroll
  for (int it = 0; it < 7; ++it) {
    int ch = it * 256 + t;
    if (ch < SCH2) {
      int k8 = ch & 7;
      int rc = ch >> 3;
      int c  = rc % SC2;
      int r  = rc / SC2;
      int y  = row0 + r, xg = x0s + c;
      v4u v = {0u, 0u, 0u, 0u};
      if (y >= 0 && y < Hd && xg >= 0 && xg < Wd)
        v = *(const v4u*)(xtb + ((y << 7) + xg) * 64 + k8 * 8);
      strip[ch ^ (c & 7)] = v;   // granule swizzle: slot k8^(c&7)
    }
  }
  __syncthreads();

  // ---- phase A: offset conv; wave -> (rowA = wv>>1, px-half = wv&1)
  v4f oacc0 = {0.f, 0.f, 0.f, 0.f};
  v4f oacc1 = {0.f, 0.f, 0.f, 0.f};
  const int rowA = wv >> 1;
  const int pxA  = ((wv & 1) << 4) + lo16;      // 0..31 within row
#pragma unroll
  for (int kk = 0; kk < 9; ++kk) {
    const int rr = kk / 3, dxk = kk % 3;
    const int sr = rowA + rr + 1;                 // strip row of integer tap
    const int c  = pxA + 1 + dxk;                 // strip col
#pragma unroll
    for (int kst = 0; kst < 2; ++kst) {
      const int k4 = kst * 4 + hi2;
      v8s bfr = *(const v8s*)&strip[(((sr * SC2 + c) * 8) + k4) ^ (c & 7)];
      // coalesced A-frags: base + lane*8 (512-elt = 1KB contiguous fragments)
      const int abase = ((kk * 2 + kst) * 2) * 512;
      v8s a0 = *(const v8s*)(woff2 + abase + lane8);
      v8s a1 = *(const v8s*)(woff2 + abase + 512 + lane8);
      oacc0 = __builtin_amdgcn_mfma_f32_16x16x32_bf16(a0, bfr, oacc0, 0, 0, 0);
      oacc1 = __builtin_amdgcn_mfma_f32_16x16x32_bf16(a1, bfr, oacc1, 0, 0, 0);
    }
  }
  {
#pragma unroll
    for (int j = 0; j < 4; ++j) {
      int oc = hi2 * 4 + j;
      pypx[rowA][pxA][oc] = oacc0[j] + b_off[oc];
    }
    if (hi2 == 0) {
#pragma unroll
      for (int j = 0; j < 2; ++j)
        pypx[rowA][pxA][16 + j] = oacc1[j] + b_off[16 + j];
    }
  }
  __syncthreads();

  // ---- phase B: wave -> (rowB = wv>>1, ci-half ksh = wv&1)
  v4f acc[4][2];
#pragma unroll
  for (int c = 0; c < 4; ++c)
#pragma unroll
    for (int p = 0; p < 2; ++p) acc[c][p] = (v4f){0.f, 0.f, 0.f, 0.f};

  const int rowB = wv >> 1;
  const int ksh  = wv & 1;
  const int hoB  = ho + rowB;
  const int pr0  = lo16, pr1 = lo16 + 16;
  const int k4   = ksh * 4 + hi2;          // this wave's granule (8 ci)

  // hoist all 18 dy/dx per pixel into registers (vector LDS reads)
  float pyA[18], pyB[18];
  {
    const float* p0 = &pypx[rowB][pr0][0];
    const float* p1 = &pypx[rowB][pr1][0];
#pragma unroll
    for (int i = 0; i < 4; ++i) {
      v4f a = *(const v4f*)(p0 + i * 4);
      v4f bb = *(const v4f*)(p1 + i * 4);
#pragma unroll
      for (int j = 0; j < 4; ++j) { pyA[i * 4 + j] = a[j]; pyB[i * 4 + j] = bb[j]; }
    }
    v2f a2 = *(const v2f*)(p0 + 16);
    v2f b2 = *(const v2f*)(p1 + 16);
    pyA[16] = a2.x; pyA[17] = a2.y;
    pyB[16] = b2.x; pyB[17] = b2.y;
  }

#pragma unroll
  for (int kk = 0; kk < 9; ++kk) {
    const int rr = kk / 3, dxk = kk % 3;
    const float byf  = (float)(hoB - 1 + rr);
    const float bxf0 = (float)(wo0 + pr0 - 1 + dxk);
    const float bxf1 = (float)(wo0 + pr1 - 1 + dxk);

    PixW a  = pixw(pyA[2 * kk], pyA[2 * kk + 1], byf, bxf0, row0, x0s);
    PixW bw = pixw(pyB[2 * kk], pyB[2 * kk + 1], byf, bxf1, row0, x0s);
    const bool viol = (!a.ok) || (!bw.ok);

    // ONE blend per pixel per kk (dedup'd: this wave's k4 granule only)
    v8s bh0 = blend_fast(strip, a.yrc, a.xrc, k4, a.w00, a.w01, a.w10, a.w11);
    v8s bh1 = blend_fast(strip, bw.yrc, bw.xrc, k4, bw.w00, bw.w01, bw.w10, bw.w11);
    if (__any(viol)) {
      if (!a.ok)
        bh0 = blend_glob(xtb, a.y0i, a.x0i, k4, a.w00, a.w01, a.w10, a.w11);
      if (!bw.ok)
        bh1 = blend_glob(xtb, bw.y0i, bw.x0i, k4, bw.w00, bw.w01, bw.w10, bw.w11);
    }

    // coalesced A-frags: base + lane*8
    const int abase = ((kk * 2 + ksh) * 4) * 512;
#pragma unroll
    for (int c = 0; c < 4; ++c) {
      v8s ah = *(const v8s*)(whi2 + abase + c * 512 + lane8);
      v8s al = *(const v8s*)(wlo2 + abase + c * 512 + lane8);
      acc[c][0] = __builtin_amdgcn_mfma_f32_16x16x32_bf16(ah, bh0, acc[c][0], 0, 0, 0);
      acc[c][1] = __builtin_amdgcn_mfma_f32_16x16x32_bf16(ah, bh1, acc[c][1], 0, 0, 0);
      acc[c][0] = __builtin_amdgcn_mfma_f32_16x16x32_bf16(al, bh0, acc[c][0], 0, 0, 0);
      acc[c][1] = __builtin_amdgcn_mfma_f32_16x16x32_bf16(al, bh1, acc[c][1], 0, 0, 0);
    }
  }

  // ---- cross-wave ci reduction: ksh=1 writes partials, ksh=0 adds+stores
  if (ksh == 1) {
#pragma unroll
    for (int c = 0; c < 4; ++c)
#pragma unroll
      for (int p = 0; p < 2; ++p)
#pragma unroll
        for (int jj = 0; jj < 4; ++jj)
          redu[rowB][c * 8 + p * 4 + jj][lane] = acc[c][p][jj];
  }
  __syncthreads();
  if (ksh == 0) {
    const int wo_b = wo0 + lo16;
#pragma unroll
    for (int c = 0; c < 4; ++c) {
#pragma unroll
      for (int p = 0; p < 2; ++p) {
#pragma unroll
        for (int jj = 0; jj < 4; ++jj) {
          float s = acc[c][p][jj] + redu[rowB][c * 8 + p * 4 + jj][lane];
          int co = c * 16 + hi2 * 4 + jj;
          out[(((size_t)b * COUT + co) * Hd + hoB) * Wd + wo_b + p * 16] = s;
        }
      }
    }
  }
}

// =================== fallback (round-3 kernel, NCHW fp32 gathers) ==========
__global__ __launch_bounds__(256, 4) void dconv_old(
    const float* __restrict__ x, const float* __restrict__ b_off,
    const ushort* __restrict__ woff_t, const ushort* __restrict__ whi,
    const ushort* __restrict__ wlo, float* __restrict__ out) {

  __shared__ uint4 colsA[64 * 8];
  __shared__ uint4 colsB[64 * 8];
  __shared__ float pypx[18][64];

  const int t    = threadIdx.x;
  const int lane = t & 63;
  const int wv   = t >> 6;
  const int lo16 = lane & 15, hi2 = lane >> 4;
  const int wid = ((blockIdx.x & 7) << 8) | (blockIdx.x >> 3);
  const int b   = wid >> 8;
  const int ho  = (wid >> 1) & 127;
  const int wo0 = (wid & 1) << 6;
  const int px = t & 63;
  const int g  = t >> 6;
  const float* xb = x + (size_t)b * (CIN * HW);

  v4f oacc0 = {0.f, 0.f, 0.f, 0.f};
  v4f oacc1 = {0.f, 0.f, 0.f, 0.f};

  for (int kk = 0; kk < 9; ++kk) {
    if (kk) __syncthreads();
    {
      int yy = ho - 1 + kk / 3;
      int xx = wo0 + px - 1 + kk % 3;
      bool vok = (yy >= 0) && (yy < Hd) && (xx >= 0) && (xx < Wd);
      const float* xp = xb + (size_t)(g * 16) * HW + yy * Wd + xx;
      uint pk[8];
#pragma unroll
      for (int u = 0; u < 16; u += 2) {
        float a0 = vok ? xp[(u + 0) * HW] : 0.f;
        float a1 = vok ? xp[(u + 1) * HW] : 0.f;
        pk[u >> 1] = f2bf_rn(a0) | (f2bf_rn(a1) << 16);
      }
      uint4 q0 = {pk[0], pk[1], pk[2], pk[3]};
      uint4 q1 = {pk[4], pk[5], pk[6], pk[7]};
      int base = px * 8, s = px & 7;
      colsA[base + ((g * 2 + 0) ^ s)] = q0;
      colsA[base + ((g * 2 + 1) ^ s)] = q1;
    }
    __syncthreads();
    int pxr = wv * 16 + lo16;
#pragma unroll
    for (int kst = 0; kst < 2; ++kst) {
      const v8s* ap0 = (const v8s*)(woff_t + (0  + lo16) * 576 + kk * 64 + kst * 32 + hi2 * 8);
      const v8s* ap1 = (const v8s*)(woff_t + (16 + lo16) * 576 + kk * 64 + kst * 32 + hi2 * 8);
      const v8s* bp  = (const v8s*)&colsA[pxr * 8 + ((kst * 4 + hi2) ^ (pxr & 7))];
      v8s bfr = *bp;
      oacc0 = __builtin_amdgcn_mfma_f32_16x16x32_bf16(*ap0, bfr, oacc0, 0, 0, 0);
      oacc1 = __builtin_amdgcn_mfma_f32_16x16x32_bf16(*ap1, bfr, oacc1, 0, 0, 0);
    }
  }
  {
    int pxw = wv * 16 + lo16;
#pragma unroll
    for (int j = 0; j < 4; ++j) {
      int oc = hi2 * 4 + j;
      pypx[oc][pxw] = oacc0[j] + b_off[oc];
    }
    if (hi2 == 0) {
#pragma unroll
      for (int j = 0; j < 2; ++j)
        pypx[16 + j][pxw] = oacc1[j] + b_off[16 + j];
    }
  }
  __syncthreads();

  v4f acc[2][2];
#pragma unroll
  for (int a = 0; a < 2; ++a)
#pragma unroll
    for (int c = 0; c < 2; ++c) acc[a][c] = (v4f){0.f, 0.f, 0.f, 0.f};

  const int co0 = (wv & 1) << 5;
  const int px0 = (wv >> 1) << 5;

  for (int kk = 0; kk < 9; ++kk) {
    if (kk) __syncthreads();
    {
      float dy = pypx[2 * kk][px], dx = pypx[2 * kk + 1][px];
      float py  = (float)(ho - 1 + kk / 3) + dy;
      float pxf = (float)(wo0 + px - 1 + kk % 3) + dx;
      float y0f = floorf(py), x0f = floorf(pxf);
      float wy1 = py - y0f,  wy0 = 1.f - wy1;
      float wx1 = pxf - x0f, wx0 = 1.f - wx1;
      bool vy0 = (y0f >= 0.f)  && (y0f < (float)Hd);
      bool vy1 = (y0f >= -1.f) && (y0f < (float)(Hd - 1));
      bool vx0 = (x0f >= 0.f)  && (x0f < (float)Wd);
      bool vx1 = (x0f >= -1.f) && (x0f < (float)(Wd - 1));
      float w00 = wy0 * wx0 * ((vy0 && vx0) ? 1.f : 0.f);
      float w01 = wy0 * wx1 * ((vy0 && vx1) ? 1.f : 0.f);
      float w10 = wy1 * wx0 * ((vy1 && vx0) ? 1.f : 0.f);
      float w11 = wy1 * wx1 * ((vy1 && vx1) ? 1.f : 0.f);
      int y0  = (int)fminf(fmaxf(y0f,       0.f), (float)(Hd - 1));
      int y1  = (int)fminf(fmaxf(y0f + 1.f, 0.f), (float)(Hd - 1));
      int x0i = (int)fminf(fmaxf(x0f,       0.f), (float)(Wd - 1));
      int x1i = (int)fminf(fmaxf(x0f + 1.f, 0.f), (float)(Wd - 1));
      const float* xp  = xb + (size_t)(g * 16) * HW;
      const float* p00 = xp + y0 * Wd + x0i;
      const float* p01 = xp + y0 * Wd + x1i;
      const float* p10 = xp + y1 * Wd + x0i;
      const float* p11 = xp + y1 * Wd + x1i;
      uint ph[8], pl[8];
#pragma unroll
      for (int u = 0; u < 16; u += 2) {
        float v0 = w00 * p00[u * HW] + w01 * p01[u * HW] +
                   w10 * p10[u * HW] + w11 * p11[u * HW];
        float v1 = w00 * p00[(u + 1) * HW] + w01 * p01[(u + 1) * HW] +
                   w10 * p10[(u + 1) * HW] + w11 * p11[(u + 1) * HW];
        uint h0, l0, h1, l1;
        split_bf(v0, h0, l0);
        split_bf(v1, h1, l1);
        ph[u >> 1] = h0 | (h1 << 16);
        pl[u >> 1] = l0 | (l1 << 16);
      }
      uint4 qh0 = {ph[0], ph[1], ph[2], ph[3]};
      uint4 qh1 = {ph[4], ph[5], ph[6], ph[7]};
      uint4 ql0 = {pl[0], pl[1], pl[2], pl[3]};
      uint4 ql1 = {pl[4], pl[5], pl[6], pl[7]};
      int base = px * 8, s = px & 7;
      colsA[base + ((g * 2 + 0) ^ s)] = qh0;
      colsA[base + ((g * 2 + 1) ^ s)] = qh1;
      colsB[base + ((g * 2 + 0) ^ s)] = ql0;
      colsB[base + ((g * 2 + 1) ^ s)] = ql1;
    }
    __syncthreads();

#pragma unroll
    for (int kst = 0; kst < 2; ++kst) {
      const int ko = kk * 64 + kst * 32 + hi2 * 8;
      v8s ah0 = *(const v8s*)(whi + (co0 +      lo16) * 576 + ko);
      v8s ah1 = *(const v8s*)(whi + (co0 + 16 + lo16) * 576 + ko);
      v8s al0 = *(const v8s*)(wlo + (co0 +      lo16) * 576 + ko);
      v8s al1 = *(const v8s*)(wlo + (co0 + 16 + lo16) * 576 + ko);
      int pr0 = px0 + lo16, pr1 = px0 + 16 + lo16;
      int k4 = kst * 4 + hi2;
      v8s bh0 = *(const v8s*)&colsA[pr0 * 8 + (k4 ^ (pr0 & 7))];
      v8s bh1 = *(const v8s*)&colsA[pr1 * 8 + (k4 ^ (pr1 & 7))];
      v8s bl0 = *(const v8s*)&colsB[pr0 * 8 + (k4 ^ (pr0 & 7))];
      v8s bl1 = *(const v8s*)&colsB[pr1 * 8 + (k4 ^ (pr1 & 7))];

      acc[0][0] = __builtin_amdgcn_mfma_f32_16x16x32_bf16(ah0, bh0, acc[0][0], 0, 0, 0);
      acc[0][0] = __builtin_amdgcn_mfma_f32_16x16x32_bf16(ah0, bl0, acc[0][0], 0, 0, 0);
      acc[0][0] = __builtin_amdgcn_mfma_f32_16x16x32_bf16(al0, bh0, acc[0][0], 0, 0, 0);
      acc[0][1] = __builtin_amdgcn_mfma_f32_16x16x32_bf16(ah0, bh1, acc[0][1], 0, 0, 0);
      acc[0][1] = __builtin_amdgcn_mfma_f32_16x16x32_bf16(ah0, bl1, acc[0][1], 0, 0, 0);
      acc[0][1] = __builtin_amdgcn_mfma_f32_16x16x32_bf16(al0, bh1, acc[0][1], 0, 0, 0);
      acc[1][0] = __builtin_amdgcn_mfma_f32_16x16x32_bf16(ah1, bh0, acc[1][0], 0, 0, 0);
      acc[1][0] = __builtin_amdgcn_mfma_f32_16x16x32_bf16(ah1, bl0, acc[1][0], 0, 0, 0);
      acc[1][0] = __builtin_amdgcn_mfma_f32_16x16x32_bf16(al1, bh0, acc[1][0], 0, 0, 0);
      acc[1][1] = __builtin_amdgcn_mfma_f32_16x16x32_bf16(ah1, bh1, acc[1][1], 0, 0, 0);
      acc[1][1] = __builtin_amdgcn_mfma_f32_16x16x32_bf16(ah1, bl1, acc[1][1], 0, 0, 0);
      acc[1][1] = __builtin_amdgcn_mfma_f32_16x16x32_bf16(al1, bh1, acc[1][1], 0, 0, 0);
    }
  }

  const int wo_b = wo0 + px0 + lo16;
#pragma unroll
  for (int ct = 0; ct < 2; ++ct) {
#pragma unroll
    for (int pt = 0; pt < 2; ++pt) {
#pragma unroll
      for (int j = 0; j < 4; ++j) {
        int co = co0 + ct * 16 + hi2 * 4 + j;
        out[(((size_t)b * COUT + co) * Hd + ho) * Wd + wo_b + pt * 16] = acc[ct][pt][j];
      }
    }
  }
}

extern "C" void kernel_launch(void* const* d_in, const int* in_sizes, int n_in,
                              void* d_out, int out_size, void* d_ws, size_t ws_size,
                              hipStream_t stream) {
  const float* x     = (const float*)d_in[0];
  const float* w_off = (const float*)d_in[1];
  const float* b_off = (const float*)d_in[2];
  const float* w     = (const float*)d_in[3];
  float* out = (float*)d_out;

  const size_t XT_ELT = (size_t)8 * HW * CIN;          // 8,388,608 ushorts
  const size_t NEED   = XT_ELT * 2 + 2u * (18432 + 36864 + 36864);

  ushort* base = (ushort*)d_ws;
  ushort *x_t, *woff_p, *whi_p, *wlo_p;
  bool fast = (ws_size >= NEED);
  if (fast) {
    x_t    = base;
    woff_p = base + XT_ELT;
  } else {
    x_t    = nullptr;
    woff_p = base;
  }
  whi_p = woff_p + 18432;
  wlo_p = whi_p + 36864;

  if (fast) {
    repack_frag<<<144, 256, 0, stream>>>(w_off, w, woff_p, whi_p, wlo_p);
    transpose_nhwc<<<8 * Hd, 256, 0, stream>>>(x, x_t);
    dconv12<<<2048, 256, 0, stream>>>(x_t, b_off, woff_p, whi_p, wlo_p, out);
  } else {
    repack_old<<<144, 256, 0, stream>>>(w_off, w, woff_p, whi_p, wlo_p);
    dconv_old<<<2048, 256, 0, stream>>>(x, b_off, woff_p, whi_p, wlo_p, out);
  }
}